// Round 1
// baseline (413.767 us; speedup 1.0000x reference)
//
#include <hip/hip_runtime.h>

// ROI adaptive average pooling — LDS-gather version, R3.
// B=8, C=1024, HW=14, N=512, FS=14, SCALE=1/16.
//
// R3 changes vs R2 (theory: kernel portion ~145us vs 65us HBM-write floor;
// LDS gather pipe is the excess):
//  1. Paired gathers: always read (O00, O00+4) and (O10, O10+4); the dw=0
//     case is masked by MW=0. Adjacent scalar loads SLP-merge into
//     ds_read2_b32 -> 8 LDS insts/quad instead of 16. Needs a ZEROED 4-float
//     pad after the planes (overread at plane 31 last element; uninit LDS
//     could be NaN and 0*NaN=NaN).
//  2. Strided position ownership {q, q+49, q+98, q+147} instead of a
//     contiguous quad: per-instruction lane addresses become stride-1 in the
//     plane -> all 32 banks, ~2 accesses/bank (free) instead of stride-4 ->
//     8 banks / ~6-way conflict on large ROIs. Store becomes 4 coalesced
//     scalar dwords (cheap).
//  3. Staging via __builtin_amdgcn_global_load_lds width=16 (no VGPR
//     round-trip, no ds_write), guarded with __has_builtin fallback.

#define FS_      14
#define PER_CH   196               // 14*14
#define C_       1024
#define CPB      32                // channels per block
#define QPC      49                // positions per thread-stride (196/4)
#define NSTAGE4  (CPB * PER_CH / 4)  // 1568 float4 to stage
#define ACT      245               // active compute threads = 5*49

#if defined(__has_builtin)
# if __has_builtin(__builtin_amdgcn_global_load_lds)
#  define USE_GLL 1
# endif
#endif

__global__ __launch_bounds__(256) void roi_pool_kernel(
    const float* __restrict__ tensor,
    const float* __restrict__ roi,
    float* __restrict__ out)
{
    __shared__ float s_plane[CPB * PER_CH + 4];   // 25,104 B (+4 zeroed pad)
    __shared__ alignas(16) int   s_o00[PER_CH], s_o10[PER_CH];  // byte offsets
    __shared__ alignas(16) float s_mw[PER_CH], s_mh[PER_CH], s_inv[PER_CH];

    const unsigned bx = blockIdx.x;
    const unsigned n  = bx >> 5;            // ROI index
    const unsigned c0 = (bx & 31u) * CPB;   // first channel of this block

    // ROI row [batch_idx, x1, y1, x2, y2] in 224-px coords (uniform -> scalar).
    const float* r = roi + n * 5;
    const int fm = (int)r[0];
    const int x1 = max((int)floorf(r[1] * 0.0625f), 0);
    const int y1 = max((int)floorf(r[2] * 0.0625f), 0);
    const int x2 = min((int)ceilf(r[3] * 0.0625f), FS_);
    const int y2 = min((int)ceilf(r[4] * 0.0625f), FS_);
    const unsigned Lh = (unsigned)(x2 - x1);   // 1..14 guaranteed
    const unsigned Lw = (unsigned)(y2 - y1);

    const unsigned tid = threadIdx.x;

    // ---- Phase 1a: geometry tables (196 positions), byte offsets into a plane.
    if (tid < PER_CH) {
        const unsigned p = tid;
        const unsigned i = p / 14u;
        const unsigned j = p - i * 14u;
        const unsigned h0 = (i * Lh) / 14u;
        const unsigned h1 = ((i + 1u) * Lh + 13u) / 14u;
        const unsigned w0 = (j * Lw) / 14u;
        const unsigned w1 = ((j + 1u) * Lw + 13u) / 14u;
        const int dh = (int)(h1 - h0) - 1;     // 0 or 1
        const int dw = (int)(w1 - w0) - 1;     // 0 or 1
        const int a00 = (x1 + (int)h0) * FS_ + (y1 + (int)w0);
        s_o00[p] = a00 * 4;
        s_o10[p] = (a00 + FS_ * dh) * 4;
        s_mw[p]  = (float)dw;
        s_mh[p]  = (float)dh;
        const int cnt = (dh + 1) * (dw + 1);   // 1, 2, or 4
        s_inv[p] = (cnt == 1) ? 1.0f : ((cnt == 2) ? 0.5f : 0.25f);
    } else if (tid < PER_CH + 4u) {
        // Zero the overread pad — MUST be deterministic (0 * pad must be 0).
        s_plane[CPB * PER_CH + (tid - PER_CH)] = 0.0f;
    }

    // ---- Phase 1b: stage the 32 contiguous input planes.
    // Slice base is 784-byte aligned -> float4-safe. LDS dest is linear
    // (wave-uniform base + lane*16), which global_load_lds requires.
    const float4* __restrict__ src4 =
        (const float4*)(tensor + ((size_t)fm * C_ + c0) * PER_CH);
    float4* __restrict__ dst4 = (float4*)s_plane;
#pragma unroll
    for (unsigned k = 0; k < 7; ++k) {
        unsigned fi = k * 256u + tid;
        if (fi < NSTAGE4) {
#if defined(USE_GLL)
            __builtin_amdgcn_global_load_lds(
                (const __attribute__((address_space(1))) void*)(src4 + fi),
                (__attribute__((address_space(3))) void*)(dst4 + fi),
                16, 0, 0);
#else
            dst4[fi] = src4[fi];
#endif
        }
    }

    __syncthreads();

    // ---- Phase 2: each active thread owns positions {q, q+49, q+98, q+147}
    // of every 5th channel. Per-lane addresses within one instruction are
    // stride-1 in the plane -> conflict-free gathers.
    if (tid < ACT) {
        const unsigned tc = tid / QPC;         // 0..4
        const unsigned q  = tid - tc * QPC;    // fixed across iterations

        int   O00[4], O10[4];
        float MW[4], MH[4], INV[4];
#pragma unroll
        for (int k = 0; k < 4; ++k) {
            const unsigned p = q + QPC * (unsigned)k;
            O00[k] = s_o00[p];
            O10[k] = s_o10[p];
            MW[k]  = s_mw[p];
            MH[k]  = s_mh[p];
            INV[k] = s_inv[p];
        }

        float* __restrict__ ob =
            out + ((size_t)n * C_ + c0) * PER_CH + q;

#pragma unroll
        for (unsigned it = 0; it < 7; ++it) {
            const unsigned cl = it * 5u + tc;  // local channel
            if (cl >= CPB) continue;           // only trims the last iteration
            const char* pb = (const char*)s_plane + cl * (PER_CH * 4);
            float* __restrict__ op = ob + cl * PER_CH;

#pragma unroll
            for (int k = 0; k < 4; ++k) {
                const char* p0 = pb + O00[k];
                const float v00 = *(const float*)(p0);
                const float v01 = *(const float*)(p0 + 4);   // pairs into ds_read2_b32
                const char* p1 = pb + O10[k];
                const float v10 = *(const float*)(p1);
                const float v11 = *(const float*)(p1 + 4);
                // v00 + MW*v01 + MH*(v10 + MW*v11), then * 1/cnt
                const float s = fmaf(MW[k], v01, v00) + MH[k] * fmaf(MW[k], v11, v10);
                op[k * QPC] = s * INV[k];      // lanes q=0..48 -> coalesced
            }
        }
    }
}

extern "C" void kernel_launch(void* const* d_in, const int* in_sizes, int n_in,
                              void* d_out, int out_size, void* d_ws, size_t ws_size,
                              hipStream_t stream) {
    const float* tensor = (const float*)d_in[0];   // [8,1024,14,14] f32
    const float* roi    = (const float*)d_in[1];   // [512,5] f32
    float* out = (float*)d_out;                    // [512,1024,14,14] f32

    const int blocks = (out_size / (CPB * PER_CH));  // 512 * 32 = 16,384
    roi_pool_kernel<<<blocks, 256, 0, stream>>>(tensor, roi, out);
}